// Round 4
// baseline (219.065 us; speedup 1.0000x reference)
//
#include <hip/hip_runtime.h>
#include <math.h>

#define B_SZ 4
#define LSEQ 2048
#define DDIM 768
#define NST  16
#define NROW (B_SZ * LSEQ)      // 8192
#define NJ   33                 // 16 B + 16 C + 1 s1

#define NC   64
#define CS   (LSEQ / NC)        // 32

// ================= projection =================
#define RB    64                // rows per block
#define KSPL  4
#define KC    (DDIM / KSPL)     // 192

// grid (128, 4), block 256: 64 rows x 4 j-groups, one K-chunk of 192.
__global__ __launch_bounds__(256) void proj_part_kernel(
    const float* __restrict__ x,
    const float* __restrict__ Wb, const float* __restrict__ Wc,
    const float* __restrict__ W1, float* __restrict__ part)
{
    __shared__ float xs[RB * (KC + 1)];   // stride 193: conflict-free b32 reads
    const int tid = threadIdx.x;
    const int row0 = blockIdx.x * RB;
    const int s = blockIdx.y;
    const int k0 = s * KC;

    // stage 64 rows x 192 floats, coalesced float4 loads
    for (int i = tid; i < RB * (KC / 4); i += 256) {
        const int r = i / (KC / 4);
        const int kq = i % (KC / 4);
        const float4 v = *(const float4*)(x + (size_t)(row0 + r) * DDIM + k0 + kq * 4);
        float* dst = xs + r * (KC + 1) + kq * 4;
        dst[0] = v.x; dst[1] = v.y; dst[2] = v.z; dst[3] = v.w;
    }
    __syncthreads();

    const int row = tid & 63;
    // jg is wave-uniform; force into SGPR so W reads become s_loads
    const int jg = __builtin_amdgcn_readfirstlane(tid >> 6);

    const float* wp[9];
    #pragma unroll
    for (int t = 0; t < 9; ++t) {
        const int j = 4 * t + jg;
        const float* wr = (j < 16) ? (Wb + j * DDIM)
                        : (j < 32) ? (Wc + (j - 16) * DDIM)
                                   : W1;               // j>=33 guarded off below
        wp[t] = wr + k0;
    }
    float acc[9];
    #pragma unroll
    for (int t = 0; t < 9; ++t) acc[t] = 0.f;

    const float* xr = xs + row * (KC + 1);
    #pragma unroll 8
    for (int k = 0; k < KC; ++k) {
        const float xv = xr[k];
        #pragma unroll
        for (int t = 0; t < 9; ++t)
            if (4 * t + jg < 33) acc[t] = fmaf(xv, wp[t][k], acc[t]);
    }
    #pragma unroll
    for (int t = 0; t < 9; ++t) {
        const int j = 4 * t + jg;
        if (j < 33)
            part[((size_t)s * NJ + j) * NROW + row0 + row] = acc[t];
    }
}

__global__ __launch_bounds__(256) void proj_reduce_kernel(
    const float* __restrict__ part,
    const float* __restrict__ bb, const float* __restrict__ bc,
    const float* __restrict__ b1,
    float* __restrict__ Bp, float* __restrict__ Cc, float* __restrict__ s1)
{
    const int idx = blockIdx.x * 256 + threadIdx.x;   // over NJ*NROW
    const int j = idx / NROW;
    const int row = idx % NROW;
    float a = 0.f;
    #pragma unroll
    for (int s = 0; s < KSPL; ++s)
        a += part[((size_t)s * NJ + j) * NROW + row];
    if (j < 16)      Bp[(size_t)row * NST + j] = a + bb[j];
    else if (j < 32) Cc[(size_t)row * NST + (j - 16)] = a + bc[j - 16];
    else             s1[row] = a + b1[0];
}

// ================= scan =================
__device__ __forceinline__ float softplus_f(float z) {
    float t = __expf(-fabsf(z));
    return fmaxf(z, 0.f) + __logf(1.f + t);
}

// e[n] = p^(n+1), depth-4 multiply tree
__device__ __forceinline__ void powers16(float p, float* e) {
    e[0] = p;      e[1] = p * p;      e[2] = e[1] * p;   e[3] = e[1] * e[1];
    e[4] = e[3] * p;  e[5] = e[3] * e[1];  e[6] = e[3] * e[2];  e[7] = e[3] * e[3];
    e[8] = e[7] * p;  e[9] = e[7] * e[1];  e[10] = e[7] * e[2]; e[11] = e[7] * e[3];
    e[12] = e[7] * e[4]; e[13] = e[7] * e[5]; e[14] = e[7] * e[6]; e[15] = e[7] * e[7];
}

__device__ __forceinline__ bool a_structured(const float* acoef) {
    bool st = true;
    #pragma unroll
    for (int n = 0; n < NST; ++n)
        st = st && (fabsf(acoef[n] - (float)(n + 1) * acoef[0]) <= 1e-5f * fabsf(acoef[n]));
    return __all(st) != 0;
}

__global__ __launch_bounds__(256) void pass1_kernel(
    const float* __restrict__ x, const float* __restrict__ A_log,
    const float* __restrict__ Wd, const float* __restrict__ bd,
    const float* __restrict__ Bp, const float* __restrict__ s1,
    float* __restrict__ Ssum, float* __restrict__ Q)
{
    const int tid = threadIdx.x;
    const int d = blockIdx.x * 256 + tid;
    const int c = blockIdx.y, b = blockIdx.z;
    const int rowbase = b * LSEQ + c * CS;

    const float wd = Wd[d], bdv = bd[d];
    float acoef[NST];
    #pragma unroll
    for (int n = 0; n < NST; ++n) acoef[n] = -__expf(A_log[d * NST + n]);
    const float a0 = acoef[0];
    const bool structured = a_structured(acoef);

    const float4* B4 = (const float4*)(Bp + (size_t)rowbase * NST);
    const float* s1p = s1 + rowbase;
    const float* xp = x + (size_t)rowbase * DDIM + d;

    float h[NST];
    #pragma unroll
    for (int n = 0; n < NST; ++n) h[n] = 0.f;
    float S = 0.f;

    if (structured) {
        #pragma unroll 4
        for (int l = 0; l < CS; ++l) {
            const float delta = softplus_f(fmaf(s1p[l], wd, bdv));
            S += delta;
            float e[NST];
            powers16(__expf(delta * a0), e);
            const float dx = delta * xp[(size_t)l * DDIM];
            const float4 b0 = B4[l * 4 + 0], b1v = B4[l * 4 + 1];
            const float4 b2 = B4[l * 4 + 2], b3v = B4[l * 4 + 3];
            const float bv[NST] = {b0.x, b0.y, b0.z, b0.w, b1v.x, b1v.y, b1v.z, b1v.w,
                                   b2.x, b2.y, b2.z, b2.w, b3v.x, b3v.y, b3v.z, b3v.w};
            #pragma unroll
            for (int n = 0; n < NST; ++n) h[n] = fmaf(e[n], h[n], dx * bv[n]);
        }
    } else {
        #pragma unroll 4
        for (int l = 0; l < CS; ++l) {
            const float delta = softplus_f(fmaf(s1p[l], wd, bdv));
            S += delta;
            float e[NST];
            #pragma unroll
            for (int n = 0; n < NST; ++n) e[n] = __expf(delta * acoef[n]);
            const float dx = delta * xp[(size_t)l * DDIM];
            const float4 b0 = B4[l * 4 + 0], b1v = B4[l * 4 + 1];
            const float4 b2 = B4[l * 4 + 2], b3v = B4[l * 4 + 3];
            const float bv[NST] = {b0.x, b0.y, b0.z, b0.w, b1v.x, b1v.y, b1v.z, b1v.w,
                                   b2.x, b2.y, b2.z, b2.w, b3v.x, b3v.y, b3v.z, b3v.w};
            #pragma unroll
            for (int n = 0; n < NST; ++n) h[n] = fmaf(e[n], h[n], dx * bv[n]);
        }
    }
    Ssum[((size_t)b * NC + c) * DDIM + d] = S;
    const size_t gbase = (((size_t)b * NC + c) * DDIM + d) * NST;
    float4* Q4 = (float4*)(Q + gbase);
    #pragma unroll
    for (int q = 0; q < 4; ++q)
        Q4[q] = make_float4(h[q * 4], h[q * 4 + 1], h[q * 4 + 2], h[q * 4 + 3]);
}

// ---------- combine v2: 4-way split of the chunk scan + shfl compose ----------
// (E2,H2) after (E1,H1):  E = E1*E2,  H = E2*H1 + H2   (associative)
#define CPG (NC / 4)   // 16 chunks per group
__global__ __launch_bounds__(256) void combine_kernel(
    const float* __restrict__ A_log,
    const float* __restrict__ Ssum, const float* __restrict__ Q,
    float* __restrict__ Hin)
{
    const int gidx = blockIdx.x * 256 + threadIdx.x;  // over B*D*N*4 = 196608
    const int lane = threadIdx.x & 63;
    const int rlow = gidx & 15;
    const int g = (gidx >> 4) & 3;
    const int hi = gidx >> 6;
    const int pairIdx = hi * 16 + rlow;               // [0, B*D*N)
    const int b = pairIdx / (DDIM * NST);
    const int r = pairIdx % (DDIM * NST);
    const int d = r >> 4;
    const float acoef = -__expf(A_log[r]);
    const int c0 = g * CPG;

    float eq[CPG], qq[CPG];
    #pragma unroll
    for (int ci = 0; ci < CPG; ++ci) {
        const size_t base = (size_t)(b * NC + c0 + ci);
        eq[ci] = __expf(acoef * Ssum[base * DDIM + d]);
        qq[ci] = Q[base * (DDIM * NST) + r];
    }
    float E = 1.f, H = 0.f;
    #pragma unroll
    for (int ci = 0; ci < CPG; ++ci) { H = fmaf(eq[ci], H, qq[ci]); E *= eq[ci]; }

    // inclusive Kogge-Stone over the 4 groups (lanes 16 apart)
    float oE = __shfl_up(E, 16, 64);
    float oH = __shfl_up(H, 16, 64);
    if (lane >= 16) { H = fmaf(E, oH, H); E *= oE; }
    oE = __shfl_up(E, 32, 64);
    oH = __shfl_up(H, 32, 64);
    if (lane >= 32) { H = fmaf(E, oH, H); E *= oE; }

    float hin = __shfl_up(H, 16, 64);   // exclusive
    if (g == 0) hin = 0.f;

    float h = hin;
    #pragma unroll
    for (int ci = 0; ci < CPG; ++ci) {
        const size_t base = (size_t)(b * NC + c0 + ci);
        Hin[base * (DDIM * NST) + r] = h;
        h = fmaf(eq[ci], h, qq[ci]);
    }
}

__global__ __launch_bounds__(256) void pass2_kernel(
    const float* __restrict__ x, const float* __restrict__ A_log,
    const float* __restrict__ Wd, const float* __restrict__ bd,
    const float* __restrict__ Bp, const float* __restrict__ Cc,
    const float* __restrict__ s1, const float* __restrict__ Hin,
    float* __restrict__ out)
{
    const int tid = threadIdx.x;
    const int d = blockIdx.x * 256 + tid;
    const int c = blockIdx.y, b = blockIdx.z;
    const int rowbase = b * LSEQ + c * CS;

    const float wd = Wd[d], bdv = bd[d];
    float acoef[NST];
    #pragma unroll
    for (int n = 0; n < NST; ++n) acoef[n] = -__expf(A_log[d * NST + n]);
    const float a0 = acoef[0];
    const bool structured = a_structured(acoef);

    const float4* B4 = (const float4*)(Bp + (size_t)rowbase * NST);
    const float4* C4 = (const float4*)(Cc + (size_t)rowbase * NST);
    const float* s1p = s1 + rowbase;
    const float* xp = x + (size_t)rowbase * DDIM + d;
    float* yp = out + (size_t)rowbase * DDIM + d;

    float h[NST];
    const size_t gbase = (((size_t)b * NC + c) * DDIM + d) * NST;
    const float4* H4 = (const float4*)(Hin + gbase);
    #pragma unroll
    for (int q = 0; q < 4; ++q) {
        const float4 hv = H4[q];
        h[q * 4] = hv.x; h[q * 4 + 1] = hv.y; h[q * 4 + 2] = hv.z; h[q * 4 + 3] = hv.w;
    }

    if (structured) {
        #pragma unroll 4
        for (int l = 0; l < CS; ++l) {
            const float delta = softplus_f(fmaf(s1p[l], wd, bdv));
            float e[NST];
            powers16(__expf(delta * a0), e);
            const float dx = delta * xp[(size_t)l * DDIM];
            const float4 b0 = B4[l * 4 + 0], b1v = B4[l * 4 + 1];
            const float4 b2 = B4[l * 4 + 2], b3v = B4[l * 4 + 3];
            const float4 c0 = C4[l * 4 + 0], c1v = C4[l * 4 + 1];
            const float4 c2 = C4[l * 4 + 2], c3v = C4[l * 4 + 3];
            const float bv[NST] = {b0.x, b0.y, b0.z, b0.w, b1v.x, b1v.y, b1v.z, b1v.w,
                                   b2.x, b2.y, b2.z, b2.w, b3v.x, b3v.y, b3v.z, b3v.w};
            const float cv[NST] = {c0.x, c0.y, c0.z, c0.w, c1v.x, c1v.y, c1v.z, c1v.w,
                                   c2.x, c2.y, c2.z, c2.w, c3v.x, c3v.y, c3v.z, c3v.w};
            float y = 0.f;
            #pragma unroll
            for (int n = 0; n < NST; ++n) {
                h[n] = fmaf(e[n], h[n], dx * bv[n]);
                y = fmaf(h[n], cv[n], y);
            }
            yp[(size_t)l * DDIM] = y;
        }
    } else {
        #pragma unroll 4
        for (int l = 0; l < CS; ++l) {
            const float delta = softplus_f(fmaf(s1p[l], wd, bdv));
            float e[NST];
            #pragma unroll
            for (int n = 0; n < NST; ++n) e[n] = __expf(delta * acoef[n]);
            const float dx = delta * xp[(size_t)l * DDIM];
            const float4 b0 = B4[l * 4 + 0], b1v = B4[l * 4 + 1];
            const float4 b2 = B4[l * 4 + 2], b3v = B4[l * 4 + 3];
            const float4 c0 = C4[l * 4 + 0], c1v = C4[l * 4 + 1];
            const float4 c2 = C4[l * 4 + 2], c3v = C4[l * 4 + 3];
            const float bv[NST] = {b0.x, b0.y, b0.z, b0.w, b1v.x, b1v.y, b1v.z, b1v.w,
                                   b2.x, b2.y, b2.z, b2.w, b3v.x, b3v.y, b3v.z, b3v.w};
            const float cv[NST] = {c0.x, c0.y, c0.z, c0.w, c1v.x, c1v.y, c1v.z, c1v.w,
                                   c2.x, c2.y, c2.z, c2.w, c3v.x, c3v.y, c3v.z, c3v.w};
            float y = 0.f;
            #pragma unroll
            for (int n = 0; n < NST; ++n) {
                h[n] = fmaf(e[n], h[n], dx * bv[n]);
                y = fmaf(h[n], cv[n], y);
            }
            yp[(size_t)l * DDIM] = y;
        }
    }
}

extern "C" void kernel_launch(void* const* d_in, const int* in_sizes, int n_in,
                              void* d_out, int out_size, void* d_ws, size_t ws_size,
                              hipStream_t stream) {
    const float* x     = (const float*)d_in[0];
    const float* A_log = (const float*)d_in[1];
    const float* Wb    = (const float*)d_in[2];
    const float* bb    = (const float*)d_in[3];
    const float* Wc    = (const float*)d_in[4];
    const float* bc    = (const float*)d_in[5];
    const float* W1    = (const float*)d_in[6];
    const float* b1    = (const float*)d_in[7];
    const float* Wd    = (const float*)d_in[8];
    const float* bd    = (const float*)d_in[9];
    float* out = (float*)d_out;

    float* ws = (float*)d_ws;
    const size_t partN = (size_t)KSPL * NJ * NROW;     // 1.08M
    const size_t BpN = (size_t)NROW * NST;             // 131072
    const size_t s1N = (size_t)NROW;                   // 8192
    const size_t sN  = (size_t)B_SZ * NC * DDIM;       // 196608
    const size_t agg = (size_t)B_SZ * NC * DDIM * NST; // 3.15M

    float* part = ws;
    float* Bp   = part + partN;
    float* Cc   = Bp + BpN;
    float* s1   = Cc + BpN;
    float* Ssum = s1 + s1N;
    float* Q    = Ssum + sN;
    float* Hin  = Q + agg;

    dim3 gproj(NROW / RB, KSPL);
    proj_part_kernel<<<gproj, 256, 0, stream>>>(x, Wb, Wc, W1, part);
    proj_reduce_kernel<<<(NJ * NROW) / 256, 256, 0, stream>>>(part, bb, bc, b1, Bp, Cc, s1);

    dim3 gscan(DDIM / 256, NC, B_SZ);
    pass1_kernel<<<gscan, 256, 0, stream>>>(x, A_log, Wd, bd, Bp, s1, Ssum, Q);

    combine_kernel<<<(B_SZ * DDIM * NST * 4) / 256, 256, 0, stream>>>(A_log, Ssum, Q, Hin);

    pass2_kernel<<<gscan, 256, 0, stream>>>(x, A_log, Wd, bd, Bp, Cc, s1, Hin, out);
}

// Round 5
// 166.421 us; speedup vs baseline: 1.3163x; 1.3163x over previous
//
#include <hip/hip_runtime.h>
#include <math.h>

#define B_SZ 4
#define LSEQ 2048
#define DDIM 768
#define NST  16
#define NROW (B_SZ * LSEQ)      // 8192
#define NJ   33                 // 16 B + 16 C + 1 s1

#define NC   128
#define CS   (LSEQ / NC)        // 16

// ================= projection: wave owns 4 rows, x in VGPRs, no LDS =================
#define RPW 4
// grid: NROW/(RPW*4) = 512 blocks, 256 threads (4 waves)
__global__ __launch_bounds__(256) void proj_kernel(
    const float* __restrict__ x,
    const float* __restrict__ Wb, const float* __restrict__ bb,
    const float* __restrict__ Wc, const float* __restrict__ bc,
    const float* __restrict__ W1, const float* __restrict__ b1,
    float* __restrict__ Bp, float* __restrict__ Cc, float* __restrict__ s1)
{
    const int lane = threadIdx.x & 63;
    const int wv   = threadIdx.x >> 6;
    const int row0 = blockIdx.x * (RPW * 4) + wv * RPW;

    // lane l holds x[row][g*256 + 4l .. 4l+3], g<3  -> coalesced 1KB/instr
    float4 xr[RPW][3];
    #pragma unroll
    for (int r = 0; r < RPW; ++r) {
        #pragma unroll
        for (int g = 0; g < 3; ++g)
            xr[r][g] = *(const float4*)(x + (size_t)(row0 + r) * DDIM + g * 256 + lane * 4);
    }

    #pragma unroll 3
    for (int j = 0; j < NJ; ++j) {
        const float* wrow = (j < 16) ? (Wb + j * DDIM)
                          : (j < 32) ? (Wc + (j - 16) * DDIM)
                                     : W1;
        float4 w[3];
        #pragma unroll
        for (int g = 0; g < 3; ++g)
            w[g] = *(const float4*)(wrow + g * 256 + lane * 4);

        float a0 = 0.f, a1 = 0.f, a2 = 0.f, a3 = 0.f;
        #pragma unroll
        for (int g = 0; g < 3; ++g) {
            a0 = fmaf(xr[0][g].x, w[g].x, a0); a0 = fmaf(xr[0][g].y, w[g].y, a0);
            a0 = fmaf(xr[0][g].z, w[g].z, a0); a0 = fmaf(xr[0][g].w, w[g].w, a0);
            a1 = fmaf(xr[1][g].x, w[g].x, a1); a1 = fmaf(xr[1][g].y, w[g].y, a1);
            a1 = fmaf(xr[1][g].z, w[g].z, a1); a1 = fmaf(xr[1][g].w, w[g].w, a1);
            a2 = fmaf(xr[2][g].x, w[g].x, a2); a2 = fmaf(xr[2][g].y, w[g].y, a2);
            a2 = fmaf(xr[2][g].z, w[g].z, a2); a2 = fmaf(xr[2][g].w, w[g].w, a2);
            a3 = fmaf(xr[3][g].x, w[g].x, a3); a3 = fmaf(xr[3][g].y, w[g].y, a3);
            a3 = fmaf(xr[3][g].z, w[g].z, a3); a3 = fmaf(xr[3][g].w, w[g].w, a3);
        }
        #pragma unroll
        for (int off = 1; off <= 32; off <<= 1) {
            a0 += __shfl_xor(a0, off, 64);
            a1 += __shfl_xor(a1, off, 64);
            a2 += __shfl_xor(a2, off, 64);
            a3 += __shfl_xor(a3, off, 64);
        }
        const float bias = (j < 16) ? bb[j] : (j < 32) ? bc[j - 16] : b1[0];
        const float v0 = a0 + bias, v1 = a1 + bias, v2 = a2 + bias, v3 = a3 + bias;
        // all lanes hold full sums; lane r writes row0+r
        if (j < 16) {
            if (lane == 0) Bp[(size_t)(row0 + 0) * NST + j] = v0;
            if (lane == 1) Bp[(size_t)(row0 + 1) * NST + j] = v1;
            if (lane == 2) Bp[(size_t)(row0 + 2) * NST + j] = v2;
            if (lane == 3) Bp[(size_t)(row0 + 3) * NST + j] = v3;
        } else if (j < 32) {
            if (lane == 0) Cc[(size_t)(row0 + 0) * NST + (j - 16)] = v0;
            if (lane == 1) Cc[(size_t)(row0 + 1) * NST + (j - 16)] = v1;
            if (lane == 2) Cc[(size_t)(row0 + 2) * NST + (j - 16)] = v2;
            if (lane == 3) Cc[(size_t)(row0 + 3) * NST + (j - 16)] = v3;
        } else {
            if (lane == 0) s1[row0 + 0] = v0;
            if (lane == 1) s1[row0 + 1] = v1;
            if (lane == 2) s1[row0 + 2] = v2;
            if (lane == 3) s1[row0 + 3] = v3;
        }
    }
}

// ================= scan =================
__device__ __forceinline__ float softplus_f(float z) {
    float t = __expf(-fabsf(z));
    return fmaxf(z, 0.f) + __logf(1.f + t);
}

// e[n] = p^(n+1), depth-4 multiply tree
__device__ __forceinline__ void powers16(float p, float* e) {
    e[0] = p;      e[1] = p * p;      e[2] = e[1] * p;   e[3] = e[1] * e[1];
    e[4] = e[3] * p;  e[5] = e[3] * e[1];  e[6] = e[3] * e[2];  e[7] = e[3] * e[3];
    e[8] = e[7] * p;  e[9] = e[7] * e[1];  e[10] = e[7] * e[2]; e[11] = e[7] * e[3];
    e[12] = e[7] * e[4]; e[13] = e[7] * e[5]; e[14] = e[7] * e[6]; e[15] = e[7] * e[7];
}

__device__ __forceinline__ bool a_structured(const float* acoef) {
    bool st = true;
    #pragma unroll
    for (int n = 0; n < NST; ++n)
        st = st && (fabsf(acoef[n] - (float)(n + 1) * acoef[0]) <= 1e-5f * fabsf(acoef[n]));
    return __all(st) != 0;
}

__global__ __launch_bounds__(256) void pass1_kernel(
    const float* __restrict__ x, const float* __restrict__ A_log,
    const float* __restrict__ Wd, const float* __restrict__ bd,
    const float* __restrict__ Bp, const float* __restrict__ s1,
    float* __restrict__ Ssum, float* __restrict__ Q)
{
    const int tid = threadIdx.x;
    const int d = blockIdx.x * 256 + tid;
    const int c = blockIdx.y, b = blockIdx.z;
    const int rowbase = b * LSEQ + c * CS;

    const float wd = Wd[d], bdv = bd[d];
    float acoef[NST];
    #pragma unroll
    for (int n = 0; n < NST; ++n) acoef[n] = -__expf(A_log[d * NST + n]);
    const float a0 = acoef[0];
    const bool structured = a_structured(acoef);

    const float4* B4 = (const float4*)(Bp + (size_t)rowbase * NST);
    const float* s1p = s1 + rowbase;
    const float* xp = x + (size_t)rowbase * DDIM + d;

    float h[NST];
    #pragma unroll
    for (int n = 0; n < NST; ++n) h[n] = 0.f;
    float S = 0.f;

    if (structured) {
        #pragma unroll 4
        for (int l = 0; l < CS; ++l) {
            const float delta = softplus_f(fmaf(s1p[l], wd, bdv));
            S += delta;
            float e[NST];
            powers16(__expf(delta * a0), e);
            const float dx = delta * xp[(size_t)l * DDIM];
            const float4 b0 = B4[l * 4 + 0], b1v = B4[l * 4 + 1];
            const float4 b2 = B4[l * 4 + 2], b3v = B4[l * 4 + 3];
            const float bv[NST] = {b0.x, b0.y, b0.z, b0.w, b1v.x, b1v.y, b1v.z, b1v.w,
                                   b2.x, b2.y, b2.z, b2.w, b3v.x, b3v.y, b3v.z, b3v.w};
            #pragma unroll
            for (int n = 0; n < NST; ++n) h[n] = fmaf(e[n], h[n], dx * bv[n]);
        }
    } else {
        #pragma unroll 4
        for (int l = 0; l < CS; ++l) {
            const float delta = softplus_f(fmaf(s1p[l], wd, bdv));
            S += delta;
            float e[NST];
            #pragma unroll
            for (int n = 0; n < NST; ++n) e[n] = __expf(delta * acoef[n]);
            const float dx = delta * xp[(size_t)l * DDIM];
            const float4 b0 = B4[l * 4 + 0], b1v = B4[l * 4 + 1];
            const float4 b2 = B4[l * 4 + 2], b3v = B4[l * 4 + 3];
            const float bv[NST] = {b0.x, b0.y, b0.z, b0.w, b1v.x, b1v.y, b1v.z, b1v.w,
                                   b2.x, b2.y, b2.z, b2.w, b3v.x, b3v.y, b3v.z, b3v.w};
            #pragma unroll
            for (int n = 0; n < NST; ++n) h[n] = fmaf(e[n], h[n], dx * bv[n]);
        }
    }
    Ssum[((size_t)b * NC + c) * DDIM + d] = S;
    const size_t gbase = (((size_t)b * NC + c) * DDIM + d) * NST;
    float4* Q4 = (float4*)(Q + gbase);
    #pragma unroll
    for (int q = 0; q < 4; ++q)
        Q4[q] = make_float4(h[q * 4], h[q * 4 + 1], h[q * 4 + 2], h[q * 4 + 3]);
}

// ---------- combine: 4-way split of the chunk scan + shfl compose ----------
// (E2,H2) after (E1,H1):  E = E1*E2,  H = E2*H1 + H2   (associative)
#define CPG (NC / 4)   // 32 chunks per group
__global__ __launch_bounds__(256) void combine_kernel(
    const float* __restrict__ A_log,
    const float* __restrict__ Ssum, const float* __restrict__ Q,
    float* __restrict__ Hin)
{
    const int gidx = blockIdx.x * 256 + threadIdx.x;  // over B*D*N*4 = 196608
    const int lane = threadIdx.x & 63;
    const int rlow = gidx & 15;
    const int g = (gidx >> 4) & 3;
    const int hi = gidx >> 6;
    const int pairIdx = hi * 16 + rlow;               // [0, B*D*N)
    const int b = pairIdx / (DDIM * NST);
    const int r = pairIdx % (DDIM * NST);
    const int d = r >> 4;
    const float acoef = -__expf(A_log[r]);
    const int c0 = g * CPG;

    float eq[CPG], qq[CPG];
    #pragma unroll
    for (int ci = 0; ci < CPG; ++ci) {
        const size_t base = (size_t)(b * NC + c0 + ci);
        eq[ci] = __expf(acoef * Ssum[base * DDIM + d]);
        qq[ci] = Q[base * (DDIM * NST) + r];
    }
    float E = 1.f, H = 0.f;
    #pragma unroll
    for (int ci = 0; ci < CPG; ++ci) { H = fmaf(eq[ci], H, qq[ci]); E *= eq[ci]; }

    // inclusive Kogge-Stone over the 4 groups (lanes 16 apart)
    float oE = __shfl_up(E, 16, 64);
    float oH = __shfl_up(H, 16, 64);
    if (lane >= 16) { H = fmaf(E, oH, H); E *= oE; }
    oE = __shfl_up(E, 32, 64);
    oH = __shfl_up(H, 32, 64);
    if (lane >= 32) { H = fmaf(E, oH, H); E *= oE; }

    float hin = __shfl_up(H, 16, 64);   // exclusive
    if (g == 0) hin = 0.f;

    float h = hin;
    #pragma unroll
    for (int ci = 0; ci < CPG; ++ci) {
        const size_t base = (size_t)(b * NC + c0 + ci);
        Hin[base * (DDIM * NST) + r] = h;
        h = fmaf(eq[ci], h, qq[ci]);
    }
}

__global__ __launch_bounds__(256) void pass2_kernel(
    const float* __restrict__ x, const float* __restrict__ A_log,
    const float* __restrict__ Wd, const float* __restrict__ bd,
    const float* __restrict__ Bp, const float* __restrict__ Cc,
    const float* __restrict__ s1, const float* __restrict__ Hin,
    float* __restrict__ out)
{
    const int tid = threadIdx.x;
    const int d = blockIdx.x * 256 + tid;
    const int c = blockIdx.y, b = blockIdx.z;
    const int rowbase = b * LSEQ + c * CS;

    const float wd = Wd[d], bdv = bd[d];
    float acoef[NST];
    #pragma unroll
    for (int n = 0; n < NST; ++n) acoef[n] = -__expf(A_log[d * NST + n]);
    const float a0 = acoef[0];
    const bool structured = a_structured(acoef);

    const float4* B4 = (const float4*)(Bp + (size_t)rowbase * NST);
    const float4* C4 = (const float4*)(Cc + (size_t)rowbase * NST);
    const float* s1p = s1 + rowbase;
    const float* xp = x + (size_t)rowbase * DDIM + d;
    float* yp = out + (size_t)rowbase * DDIM + d;

    float h[NST];
    const size_t gbase = (((size_t)b * NC + c) * DDIM + d) * NST;
    const float4* H4 = (const float4*)(Hin + gbase);
    #pragma unroll
    for (int q = 0; q < 4; ++q) {
        const float4 hv = H4[q];
        h[q * 4] = hv.x; h[q * 4 + 1] = hv.y; h[q * 4 + 2] = hv.z; h[q * 4 + 3] = hv.w;
    }

    if (structured) {
        #pragma unroll 4
        for (int l = 0; l < CS; ++l) {
            const float delta = softplus_f(fmaf(s1p[l], wd, bdv));
            float e[NST];
            powers16(__expf(delta * a0), e);
            const float dx = delta * xp[(size_t)l * DDIM];
            const float4 b0 = B4[l * 4 + 0], b1v = B4[l * 4 + 1];
            const float4 b2 = B4[l * 4 + 2], b3v = B4[l * 4 + 3];
            const float4 c0 = C4[l * 4 + 0], c1v = C4[l * 4 + 1];
            const float4 c2 = C4[l * 4 + 2], c3v = C4[l * 4 + 3];
            const float bv[NST] = {b0.x, b0.y, b0.z, b0.w, b1v.x, b1v.y, b1v.z, b1v.w,
                                   b2.x, b2.y, b2.z, b2.w, b3v.x, b3v.y, b3v.z, b3v.w};
            const float cv[NST] = {c0.x, c0.y, c0.z, c0.w, c1v.x, c1v.y, c1v.z, c1v.w,
                                   c2.x, c2.y, c2.z, c2.w, c3v.x, c3v.y, c3v.z, c3v.w};
            float y = 0.f;
            #pragma unroll
            for (int n = 0; n < NST; ++n) {
                h[n] = fmaf(e[n], h[n], dx * bv[n]);
                y = fmaf(h[n], cv[n], y);
            }
            yp[(size_t)l * DDIM] = y;
        }
    } else {
        #pragma unroll 4
        for (int l = 0; l < CS; ++l) {
            const float delta = softplus_f(fmaf(s1p[l], wd, bdv));
            float e[NST];
            #pragma unroll
            for (int n = 0; n < NST; ++n) e[n] = __expf(delta * acoef[n]);
            const float dx = delta * xp[(size_t)l * DDIM];
            const float4 b0 = B4[l * 4 + 0], b1v = B4[l * 4 + 1];
            const float4 b2 = B4[l * 4 + 2], b3v = B4[l * 4 + 3];
            const float4 c0 = C4[l * 4 + 0], c1v = C4[l * 4 + 1];
            const float4 c2 = C4[l * 4 + 2], c3v = C4[l * 4 + 3];
            const float bv[NST] = {b0.x, b0.y, b0.z, b0.w, b1v.x, b1v.y, b1v.z, b1v.w,
                                   b2.x, b2.y, b2.z, b2.w, b3v.x, b3v.y, b3v.z, b3v.w};
            const float cv[NST] = {c0.x, c0.y, c0.z, c0.w, c1v.x, c1v.y, c1v.z, c1v.w,
                                   c2.x, c2.y, c2.z, c2.w, c3v.x, c3v.y, c3v.z, c3v.w};
            float y = 0.f;
            #pragma unroll
            for (int n = 0; n < NST; ++n) {
                h[n] = fmaf(e[n], h[n], dx * bv[n]);
                y = fmaf(h[n], cv[n], y);
            }
            yp[(size_t)l * DDIM] = y;
        }
    }
}

extern "C" void kernel_launch(void* const* d_in, const int* in_sizes, int n_in,
                              void* d_out, int out_size, void* d_ws, size_t ws_size,
                              hipStream_t stream) {
    const float* x     = (const float*)d_in[0];
    const float* A_log = (const float*)d_in[1];
    const float* Wb    = (const float*)d_in[2];
    const float* bb    = (const float*)d_in[3];
    const float* Wc    = (const float*)d_in[4];
    const float* bc    = (const float*)d_in[5];
    const float* W1    = (const float*)d_in[6];
    const float* b1    = (const float*)d_in[7];
    const float* Wd    = (const float*)d_in[8];
    const float* bd    = (const float*)d_in[9];
    float* out = (float*)d_out;

    float* ws = (float*)d_ws;
    const size_t BpN = (size_t)NROW * NST;             // 131072
    const size_t s1N = (size_t)NROW;                   // 8192
    const size_t sN  = (size_t)B_SZ * NC * DDIM;       // 393216
    const size_t agg = (size_t)B_SZ * NC * DDIM * NST; // 6.29M

    float* Bp   = ws;
    float* Cc   = Bp + BpN;
    float* s1   = Cc + BpN;
    float* Ssum = s1 + s1N;
    float* Q    = Ssum + sN;
    float* Hin  = Q + agg;

    proj_kernel<<<NROW / (RPW * 4), 256, 0, stream>>>(x, Wb, bb, Wc, bc, W1, b1, Bp, Cc, s1);

    dim3 gscan(DDIM / 256, NC, B_SZ);
    pass1_kernel<<<gscan, 256, 0, stream>>>(x, A_log, Wd, bd, Bp, s1, Ssum, Q);

    combine_kernel<<<(B_SZ * DDIM * NST * 4) / 256, 256, 0, stream>>>(A_log, Ssum, Q, Hin);

    pass2_kernel<<<gscan, 256, 0, stream>>>(x, A_log, Wd, bd, Bp, Cc, s1, Hin, out);
}

// Round 6
// 155.651 us; speedup vs baseline: 1.4074x; 1.0692x over previous
//
#include <hip/hip_runtime.h>
#include <math.h>

#define B_SZ 4
#define LSEQ 2048
#define DDIM 768
#define NST  16
#define NROW (B_SZ * LSEQ)      // 8192
#define NJ   33                 // 16 B + 16 C + 1 s1

#define NC   128
#define CS   (LSEQ / NC)        // 16

// ================= projection: thread=(row, k-slice), W via s_load =================
#define KSPL 32
#define KCH  (DDIM / KSPL)      // 24 floats per slice

// grid (NROW/256, KSPL) = (32, 32), block 256. lane = row -> W addr wave-uniform.
__global__ __launch_bounds__(256) void proj_part_kernel(
    const float* __restrict__ x,
    const float* __restrict__ Wb, const float* __restrict__ Wc,
    const float* __restrict__ W1, float* __restrict__ part)
{
    const int row = blockIdx.x * 256 + threadIdx.x;
    const int s = blockIdx.y;
    const int k0 = s * KCH;

    // 24 x-floats in registers (6 float4, 16B-aligned since 24*4B=96B)
    float4 xv[6];
    const float* xp = x + (size_t)row * DDIM + k0;
    #pragma unroll
    for (int q = 0; q < 6; ++q) xv[q] = *(const float4*)(xp + q * 4);

    float acc[NJ];
    #pragma unroll
    for (int j = 0; j < NJ; ++j) {
        const float* wrow = (j < 16) ? (Wb + j * DDIM)
                          : (j < 32) ? (Wc + (j - 16) * DDIM)
                                     : W1;
        const float* wk = wrow + k0;   // lane-invariant -> s_load stream
        float a = 0.f;
        #pragma unroll
        for (int q = 0; q < 6; ++q) {
            a = fmaf(xv[q].x, wk[q * 4 + 0], a);
            a = fmaf(xv[q].y, wk[q * 4 + 1], a);
            a = fmaf(xv[q].z, wk[q * 4 + 2], a);
            a = fmaf(xv[q].w, wk[q * 4 + 3], a);
        }
        acc[j] = a;
    }
    #pragma unroll
    for (int j = 0; j < NJ; ++j)
        part[((size_t)s * NJ + j) * NROW + row] = acc[j];
}

// idx over NJ*NROW; sums KSPL partials, adds bias, scatters to Bp/Cc/s1
__global__ __launch_bounds__(256) void proj_reduce_kernel(
    const float* __restrict__ part,
    const float* __restrict__ bb, const float* __restrict__ bc,
    const float* __restrict__ b1,
    float* __restrict__ Bp, float* __restrict__ Cc, float* __restrict__ s1)
{
    const int idx = blockIdx.x * 256 + threadIdx.x;
    if (idx >= NJ * NROW) return;
    const int j = idx / NROW;
    const int row = idx % NROW;
    float a = 0.f;
    #pragma unroll 8
    for (int s = 0; s < KSPL; ++s)
        a += part[((size_t)s * NJ + j) * NROW + row];
    if (j < 16)      Bp[(size_t)row * NST + j] = a + bb[j];
    else if (j < 32) Cc[(size_t)row * NST + (j - 16)] = a + bc[j - 16];
    else             s1[row] = a + b1[0];
}

// ================= scan =================
__device__ __forceinline__ float softplus_f(float z) {
    float t = __expf(-fabsf(z));
    return fmaxf(z, 0.f) + __logf(1.f + t);
}

// e[n] = p^(n+1), depth-4 multiply tree
__device__ __forceinline__ void powers16(float p, float* e) {
    e[0] = p;      e[1] = p * p;      e[2] = e[1] * p;   e[3] = e[1] * e[1];
    e[4] = e[3] * p;  e[5] = e[3] * e[1];  e[6] = e[3] * e[2];  e[7] = e[3] * e[3];
    e[8] = e[7] * p;  e[9] = e[7] * e[1];  e[10] = e[7] * e[2]; e[11] = e[7] * e[3];
    e[12] = e[7] * e[4]; e[13] = e[7] * e[5]; e[14] = e[7] * e[6]; e[15] = e[7] * e[7];
}

__device__ __forceinline__ bool a_structured(const float* acoef) {
    bool st = true;
    #pragma unroll
    for (int n = 0; n < NST; ++n)
        st = st && (fabsf(acoef[n] - (float)(n + 1) * acoef[0]) <= 1e-5f * fabsf(acoef[n]));
    return __all(st) != 0;
}

__global__ __launch_bounds__(256) void pass1_kernel(
    const float* __restrict__ x, const float* __restrict__ A_log,
    const float* __restrict__ Wd, const float* __restrict__ bd,
    const float* __restrict__ Bp, const float* __restrict__ s1,
    float* __restrict__ Ssum, float* __restrict__ Q)
{
    const int tid = threadIdx.x;
    const int d = blockIdx.x * 256 + tid;
    const int c = blockIdx.y, b = blockIdx.z;
    const int rowbase = b * LSEQ + c * CS;

    const float wd = Wd[d], bdv = bd[d];
    float acoef[NST];
    #pragma unroll
    for (int n = 0; n < NST; ++n) acoef[n] = -__expf(A_log[d * NST + n]);
    const float a0 = acoef[0];
    const bool structured = a_structured(acoef);

    const float4* B4 = (const float4*)(Bp + (size_t)rowbase * NST);
    const float* s1p = s1 + rowbase;
    const float* xp = x + (size_t)rowbase * DDIM + d;

    float h[NST];
    #pragma unroll
    for (int n = 0; n < NST; ++n) h[n] = 0.f;
    float S = 0.f;

    if (structured) {
        #pragma unroll 4
        for (int l = 0; l < CS; ++l) {
            const float delta = softplus_f(fmaf(s1p[l], wd, bdv));
            S += delta;
            float e[NST];
            powers16(__expf(delta * a0), e);
            const float dx = delta * xp[(size_t)l * DDIM];
            const float4 b0 = B4[l * 4 + 0], b1v = B4[l * 4 + 1];
            const float4 b2 = B4[l * 4 + 2], b3v = B4[l * 4 + 3];
            const float bv[NST] = {b0.x, b0.y, b0.z, b0.w, b1v.x, b1v.y, b1v.z, b1v.w,
                                   b2.x, b2.y, b2.z, b2.w, b3v.x, b3v.y, b3v.z, b3v.w};
            #pragma unroll
            for (int n = 0; n < NST; ++n) h[n] = fmaf(e[n], h[n], dx * bv[n]);
        }
    } else {
        #pragma unroll 4
        for (int l = 0; l < CS; ++l) {
            const float delta = softplus_f(fmaf(s1p[l], wd, bdv));
            S += delta;
            float e[NST];
            #pragma unroll
            for (int n = 0; n < NST; ++n) e[n] = __expf(delta * acoef[n]);
            const float dx = delta * xp[(size_t)l * DDIM];
            const float4 b0 = B4[l * 4 + 0], b1v = B4[l * 4 + 1];
            const float4 b2 = B4[l * 4 + 2], b3v = B4[l * 4 + 3];
            const float bv[NST] = {b0.x, b0.y, b0.z, b0.w, b1v.x, b1v.y, b1v.z, b1v.w,
                                   b2.x, b2.y, b2.z, b2.w, b3v.x, b3v.y, b3v.z, b3v.w};
            #pragma unroll
            for (int n = 0; n < NST; ++n) h[n] = fmaf(e[n], h[n], dx * bv[n]);
        }
    }
    Ssum[((size_t)b * NC + c) * DDIM + d] = S;
    const size_t gbase = (((size_t)b * NC + c) * DDIM + d) * NST;
    float4* Q4 = (float4*)(Q + gbase);
    #pragma unroll
    for (int q = 0; q < 4; ++q)
        Q4[q] = make_float4(h[q * 4], h[q * 4 + 1], h[q * 4 + 2], h[q * 4 + 3]);
}

// ---------- combine: 4-way split of the chunk scan + shfl compose ----------
// (E2,H2) after (E1,H1):  E = E1*E2,  H = E2*H1 + H2   (associative)
#define CPG (NC / 4)   // 32 chunks per group
__global__ __launch_bounds__(256) void combine_kernel(
    const float* __restrict__ A_log,
    const float* __restrict__ Ssum, const float* __restrict__ Q,
    float* __restrict__ Hin)
{
    const int gidx = blockIdx.x * 256 + threadIdx.x;  // over B*D*N*4 = 196608
    const int lane = threadIdx.x & 63;
    const int rlow = gidx & 15;
    const int g = (gidx >> 4) & 3;
    const int hi = gidx >> 6;
    const int pairIdx = hi * 16 + rlow;               // [0, B*D*N)
    const int b = pairIdx / (DDIM * NST);
    const int r = pairIdx % (DDIM * NST);
    const int d = r >> 4;
    const float acoef = -__expf(A_log[r]);
    const int c0 = g * CPG;

    float eq[CPG], qq[CPG];
    #pragma unroll
    for (int ci = 0; ci < CPG; ++ci) {
        const size_t base = (size_t)(b * NC + c0 + ci);
        eq[ci] = __expf(acoef * Ssum[base * DDIM + d]);
        qq[ci] = Q[base * (DDIM * NST) + r];
    }
    float E = 1.f, H = 0.f;
    #pragma unroll
    for (int ci = 0; ci < CPG; ++ci) { H = fmaf(eq[ci], H, qq[ci]); E *= eq[ci]; }

    // inclusive Kogge-Stone over the 4 groups (lanes 16 apart)
    float oE = __shfl_up(E, 16, 64);
    float oH = __shfl_up(H, 16, 64);
    if (lane >= 16) { H = fmaf(E, oH, H); E *= oE; }
    oE = __shfl_up(E, 32, 64);
    oH = __shfl_up(H, 32, 64);
    if (lane >= 32) { H = fmaf(E, oH, H); E *= oE; }

    float hin = __shfl_up(H, 16, 64);   // exclusive
    if (g == 0) hin = 0.f;

    float h = hin;
    #pragma unroll
    for (int ci = 0; ci < CPG; ++ci) {
        const size_t base = (size_t)(b * NC + c0 + ci);
        Hin[base * (DDIM * NST) + r] = h;
        h = fmaf(eq[ci], h, qq[ci]);
    }
}

__global__ __launch_bounds__(256) void pass2_kernel(
    const float* __restrict__ x, const float* __restrict__ A_log,
    const float* __restrict__ Wd, const float* __restrict__ bd,
    const float* __restrict__ Bp, const float* __restrict__ Cc,
    const float* __restrict__ s1, const float* __restrict__ Hin,
    float* __restrict__ out)
{
    const int tid = threadIdx.x;
    const int d = blockIdx.x * 256 + tid;
    const int c = blockIdx.y, b = blockIdx.z;
    const int rowbase = b * LSEQ + c * CS;

    const float wd = Wd[d], bdv = bd[d];
    float acoef[NST];
    #pragma unroll
    for (int n = 0; n < NST; ++n) acoef[n] = -__expf(A_log[d * NST + n]);
    const float a0 = acoef[0];
    const bool structured = a_structured(acoef);

    const float4* B4 = (const float4*)(Bp + (size_t)rowbase * NST);
    const float4* C4 = (const float4*)(Cc + (size_t)rowbase * NST);
    const float* s1p = s1 + rowbase;
    const float* xp = x + (size_t)rowbase * DDIM + d;
    float* yp = out + (size_t)rowbase * DDIM + d;

    float h[NST];
    const size_t gbase = (((size_t)b * NC + c) * DDIM + d) * NST;
    const float4* H4 = (const float4*)(Hin + gbase);
    #pragma unroll
    for (int q = 0; q < 4; ++q) {
        const float4 hv = H4[q];
        h[q * 4] = hv.x; h[q * 4 + 1] = hv.y; h[q * 4 + 2] = hv.z; h[q * 4 + 3] = hv.w;
    }

    if (structured) {
        #pragma unroll 4
        for (int l = 0; l < CS; ++l) {
            const float delta = softplus_f(fmaf(s1p[l], wd, bdv));
            float e[NST];
            powers16(__expf(delta * a0), e);
            const float dx = delta * xp[(size_t)l * DDIM];
            const float4 b0 = B4[l * 4 + 0], b1v = B4[l * 4 + 1];
            const float4 b2 = B4[l * 4 + 2], b3v = B4[l * 4 + 3];
            const float4 c0 = C4[l * 4 + 0], c1v = C4[l * 4 + 1];
            const float4 c2 = C4[l * 4 + 2], c3v = C4[l * 4 + 3];
            const float bv[NST] = {b0.x, b0.y, b0.z, b0.w, b1v.x, b1v.y, b1v.z, b1v.w,
                                   b2.x, b2.y, b2.z, b2.w, b3v.x, b3v.y, b3v.z, b3v.w};
            const float cv[NST] = {c0.x, c0.y, c0.z, c0.w, c1v.x, c1v.y, c1v.z, c1v.w,
                                   c2.x, c2.y, c2.z, c2.w, c3v.x, c3v.y, c3v.z, c3v.w};
            float y = 0.f;
            #pragma unroll
            for (int n = 0; n < NST; ++n) {
                h[n] = fmaf(e[n], h[n], dx * bv[n]);
                y = fmaf(h[n], cv[n], y);
            }
            yp[(size_t)l * DDIM] = y;
        }
    } else {
        #pragma unroll 4
        for (int l = 0; l < CS; ++l) {
            const float delta = softplus_f(fmaf(s1p[l], wd, bdv));
            float e[NST];
            #pragma unroll
            for (int n = 0; n < NST; ++n) e[n] = __expf(delta * acoef[n]);
            const float dx = delta * xp[(size_t)l * DDIM];
            const float4 b0 = B4[l * 4 + 0], b1v = B4[l * 4 + 1];
            const float4 b2 = B4[l * 4 + 2], b3v = B4[l * 4 + 3];
            const float4 c0 = C4[l * 4 + 0], c1v = C4[l * 4 + 1];
            const float4 c2 = C4[l * 4 + 2], c3v = C4[l * 4 + 3];
            const float bv[NST] = {b0.x, b0.y, b0.z, b0.w, b1v.x, b1v.y, b1v.z, b1v.w,
                                   b2.x, b2.y, b2.z, b2.w, b3v.x, b3v.y, b3v.z, b3v.w};
            const float cv[NST] = {c0.x, c0.y, c0.z, c0.w, c1v.x, c1v.y, c1v.z, c1v.w,
                                   c2.x, c2.y, c2.z, c2.w, c3v.x, c3v.y, c3v.z, c3v.w};
            float y = 0.f;
            #pragma unroll
            for (int n = 0; n < NST; ++n) {
                h[n] = fmaf(e[n], h[n], dx * bv[n]);
                y = fmaf(h[n], cv[n], y);
            }
            yp[(size_t)l * DDIM] = y;
        }
    }
}

extern "C" void kernel_launch(void* const* d_in, const int* in_sizes, int n_in,
                              void* d_out, int out_size, void* d_ws, size_t ws_size,
                              hipStream_t stream) {
    const float* x     = (const float*)d_in[0];
    const float* A_log = (const float*)d_in[1];
    const float* Wb    = (const float*)d_in[2];
    const float* bb    = (const float*)d_in[3];
    const float* Wc    = (const float*)d_in[4];
    const float* bc    = (const float*)d_in[5];
    const float* W1    = (const float*)d_in[6];
    const float* b1    = (const float*)d_in[7];
    const float* Wd    = (const float*)d_in[8];
    const float* bd    = (const float*)d_in[9];
    float* out = (float*)d_out;

    float* ws = (float*)d_ws;
    const size_t partN = (size_t)KSPL * NJ * NROW;     // 8.65M floats = 34.6MB
    const size_t BpN = (size_t)NROW * NST;             // 131072
    const size_t s1N = (size_t)NROW;                   // 8192
    const size_t sN  = (size_t)B_SZ * NC * DDIM;       // 393216
    const size_t agg = (size_t)B_SZ * NC * DDIM * NST; // 6.29M

    float* part = ws;
    float* Bp   = part + partN;
    float* Cc   = Bp + BpN;
    float* s1   = Cc + BpN;
    float* Ssum = s1 + s1N;
    float* Q    = Ssum + sN;
    float* Hin  = Q + agg;

    dim3 gproj(NROW / 256, KSPL);
    proj_part_kernel<<<gproj, 256, 0, stream>>>(x, Wb, Wc, W1, part);
    proj_reduce_kernel<<<(NJ * NROW + 255) / 256, 256, 0, stream>>>(part, bb, bc, b1, Bp, Cc, s1);

    dim3 gscan(DDIM / 256, NC, B_SZ);
    pass1_kernel<<<gscan, 256, 0, stream>>>(x, A_log, Wd, bd, Bp, s1, Ssum, Q);

    combine_kernel<<<(B_SZ * DDIM * NST * 4) / 256, 256, 0, stream>>>(A_log, Ssum, Q, Hin);

    pass2_kernel<<<gscan, 256, 0, stream>>>(x, A_log, Wd, bd, Bp, Cc, s1, Hin, out);
}